// Round 13
// baseline (1419.269 us; speedup 1.0000x reference)
//
// EncoderModel forward, MI355X/gfx950. Round 13 (base = round-12 best 1338us):
// quarter-split attention: 1024 blocks = (b,h,qh,kh), 8 waves, 80KB LDS ->
// 2 blocks/CU (was 160KB/1 block). kv-halves merged by a flash-merge kernel
// (bf16 partials + f32 m,l in exp2 domain). All else identical to round 12.
#include <hip/hip_runtime.h>

#define BB 32
#define SS 512
#define DD 512
#define HH 8
#define HDH 64
#define LL 6
#define DFF 2048
#define MM (BB*SS)

typedef __attribute__((ext_vector_type(4))) float f32x4;
typedef __attribute__((ext_vector_type(8))) short s16x8;
typedef __attribute__((ext_vector_type(4))) short s16x4;

__device__ __forceinline__ unsigned short f2bf(float f) {
    union { float f; unsigned u; } v; v.f = f;
    unsigned r = v.u + 0x7fffu + ((v.u >> 16) & 1u);
    return (unsigned short)(r >> 16);
}
__device__ __forceinline__ float bf2f(unsigned short b) {
    union { unsigned u; float f; } v; v.u = ((unsigned)b) << 16;
    return v.f;
}
__device__ __forceinline__ float exp2_fast(float x) {
    float r; asm("v_exp_f32 %0, %1" : "=v"(r) : "v"(x)); return r;
}

__device__ __forceinline__ f32x4 mfma_bf16(s16x8 a, s16x8 b, f32x4 c) {
    asm("v_mfma_f32_16x16x32_bf16 %0, %1, %2, %0" : "+v"(c) : "v"(a), "v"(b));
    return c;
}

__device__ __forceinline__ void gload_lds16(const void* g, void* l) {
    __builtin_amdgcn_global_load_lds(
        (__attribute__((address_space(1))) void*)g,
        (__attribute__((address_space(3))) void*)l, 16, 0, 0);
}

// ---- LDS 64x64 tile transpose-convert: f32 [K][N] tile -> bf16 [N][K] -----
__device__ __forceinline__ void tile_transpose_conv(
    const float* __restrict__ src, int srcPitch,
    unsigned short* __restrict__ dst, int dstPitch,
    float* lt, float scale)
{
    const int t = threadIdx.x;
    #pragma unroll
    for (int it = 0; it < 4; ++it) {
        int r = it * 16 + (t >> 4);
        int c = (t & 15) * 4;
        f32x4 v = *(const f32x4*)(src + (size_t)r * srcPitch + c);
        lt[r * 65 + c + 0] = v[0];
        lt[r * 65 + c + 1] = v[1];
        lt[r * 65 + c + 2] = v[2];
        lt[r * 65 + c + 3] = v[3];
    }
    __syncthreads();
    int nn = t >> 2;
    int kc = (t & 3) * 16;
    s16x8 o0, o1;
    #pragma unroll
    for (int i = 0; i < 8; ++i)  o0[i] = (short)f2bf(lt[(kc + i) * 65 + nn] * scale);
    #pragma unroll
    for (int i = 0; i < 8; ++i)  o1[i] = (short)f2bf(lt[(kc + 8 + i) * 65 + nn] * scale);
    *(s16x8*)(dst + (size_t)nn * dstPitch + kc) = o0;
    *(s16x8*)(dst + (size_t)nn * dstPitch + kc + 8) = o1;
}

// Merged weight conversion (one dispatch)
__global__ __launch_bounds__(256) void k_tconv_all(
    const float* __restrict__ Wq, const float* __restrict__ Wk,
    const float* __restrict__ Wv, const float* __restrict__ Wo,
    const float* __restrict__ W1, const float* __restrict__ W2,
    unsigned short* __restrict__ wqkv_t, unsigned short* __restrict__ wo_t,
    unsigned short* __restrict__ w1_t, unsigned short* __restrict__ w2_t)
{
    __shared__ float lt[64 * 65];
    int bid = blockIdx.x;
    if (bid < 1152) {
        int which = bid / 384;
        int rem = bid - which * 384;
        int l = rem >> 6;
        int h = (rem >> 3) & 7;
        int kt = rem & 7;
        const float* W = which == 0 ? Wq : (which == 1 ? Wk : Wv);
        float scale = (which == 1) ? 0.18033688011116048f : 1.0f;  // 0.125*log2(e)
        const float* srcT = W + (((size_t)(l * HH + h) * 512) + kt * 64) * 64;
        unsigned short* dstT = wqkv_t + ((size_t)l * 1536 + which * 512 + h * 64) * 512 + kt * 64;
        tile_transpose_conv(srcT, 64, dstT, 512, lt, scale);
        return;
    }
    const float* src; unsigned short* dst; int K, N, rem;
    if (bid < 1536)      { src = Wo; dst = wo_t; K = 512;  N = 512;  rem = bid - 1152; }
    else if (bid < 3072) { src = W1; dst = w1_t; K = 512;  N = 2048; rem = bid - 1536; }
    else                 { src = W2; dst = w2_t; K = 2048; N = 512;  rem = bid - 3072; }
    int tpb = (K >> 6) * (N >> 6);
    int l = rem / tpb;
    int r2 = rem - l * tpb;
    int kt = r2 / (N >> 6);
    int ntile = r2 - kt * (N >> 6);
    const float* srcT = src + (size_t)l * K * N + (size_t)(kt * 64) * N + ntile * 64;
    unsigned short* dstT = dst + (size_t)l * N * K + (size_t)(ntile * 64) * K + kt * 64;
    tile_transpose_conv(srcT, N, dstT, K, lt, 1.0f);
}

// ---- embedding + positional encoding -> hi/lo bf16 pair ----
__global__ __launch_bounds__(256) void k_embed(const int* __restrict__ tokens,
                                               const float* __restrict__ emb,
                                               const float* __restrict__ pe,
                                               unsigned short* __restrict__ xh,
                                               unsigned short* __restrict__ xl) {
    int i = blockIdx.x * 256 + threadIdx.x;
    int row = i >> 7;
    int d4 = (i & 127) * 4;
    int srow = row & (SS - 1);
    int tok = tokens[row];
    f32x4 ev = *(const f32x4*)(emb + (size_t)tok*DD + d4);
    f32x4 pv = *(const f32x4*)(pe + (size_t)srow*DD + d4);
    s16x4 hv, lv;
    #pragma unroll
    for (int j = 0; j < 4; ++j) {
        float v = ev[j] + pv[j];
        unsigned short hi = f2bf(v);
        hv[j] = (short)hi;
        lv[j] = (short)f2bf(v - bf2f(hi));
    }
    *(s16x4*)(xh + (size_t)row*DD + d4) = hv;
    *(s16x4*)(xl + (size_t)row*DD + d4) = lv;
}

// ---- fused residual + layernorm; residual = (xh,xl) bf16 pair, y bf16 ----
__global__ __launch_bounds__(128) void k_ln(unsigned short* xh,
                                            unsigned short* xl,
                                            const unsigned short* __restrict__ y,
                                            const float* __restrict__ gg,
                                            const float* __restrict__ bb,
                                            float* __restrict__ xo) {
    const int row = blockIdx.x;
    const int tid = threadIdx.x;
    __shared__ float red[4];
    s16x4 hv0 = *(const s16x4*)(xh + (size_t)row*DD + tid*4);
    s16x4 lv0 = *(const s16x4*)(xl + (size_t)row*DD + tid*4);
    s16x4 yv = *(const s16x4*)(y + (size_t)row*DD + tid*4);
    f32x4 vv;
    #pragma unroll
    for (int j = 0; j < 4; ++j)
        vv[j] = (bf2f((unsigned short)hv0[j]) + bf2f((unsigned short)lv0[j]))
                + bf2f((unsigned short)yv[j]);
    float sum = vv[0] + vv[1] + vv[2] + vv[3];
    #pragma unroll
    for (int off = 1; off < 64; off <<= 1) sum += __shfl_xor(sum, off);
    if ((tid & 63) == 0) red[tid >> 6] = sum;
    __syncthreads();
    float mu = (red[0] + red[1]) * (1.0f / 512.0f);
    float s2 = 0.0f;
    #pragma unroll
    for (int j = 0; j < 4; ++j) { float d = vv[j] - mu; s2 += d * d; }
    #pragma unroll
    for (int off = 1; off < 64; off <<= 1) s2 += __shfl_xor(s2, off);
    if ((tid & 63) == 0) red[2 + (tid >> 6)] = s2;
    __syncthreads();
    float var = (red[2] + red[3]) * (1.0f / 512.0f);
    float rs = rsqrtf(var + 1e-5f);
    f32x4 gv = *(const f32x4*)(gg + tid*4);
    f32x4 bv = *(const f32x4*)(bb + tid*4);
    s16x4 hv, lv;
    f32x4 ov;
    #pragma unroll
    for (int j = 0; j < 4; ++j) {
        float o = (vv[j] - mu) * rs * gv[j] + bv[j];
        ov[j] = o;
        unsigned short hi = f2bf(o);
        hv[j] = (short)hi;
        lv[j] = (short)f2bf(o - bf2f(hi));
    }
    *(s16x4*)(xh + (size_t)row*DD + tid*4) = hv;
    *(s16x4*)(xl + (size_t)row*DD + tid*4) = lv;
    if (xo) *(f32x4*)(xo + (size_t)row*DD + tid*4) = ov;
}

// ---- GEMM (2-phase 128x128, proven): C = A @ Bt^T ----
template<int EPI>
__global__ __launch_bounds__(256, 2) void k_gemm(
    const unsigned short* __restrict__ A, const unsigned short* __restrict__ Bt,
    unsigned short* __restrict__ ob,
    const float* __restrict__ bias, int N, int K, int nt)
{
    __shared__ short lds[2][2][4096];
    const int tid = threadIdx.x;
    const int lane = tid & 63;
    const int wid = tid >> 6;
    const int g = lane >> 4;
    const int t16 = lane & 15;

    int nwg = gridDim.x;
    int bid = blockIdx.x;
    int cpx = nwg >> 3;
    int swz = (bid & 7) * cpx + (bid >> 3);
    int bm = swz / nt;
    int bn = swz - bm * nt;

    const unsigned short* Ag = A  + (size_t)bm * 128 * K;
    const unsigned short* Bg = Bt + (size_t)bn * 128 * K;

    auto stage = [&](int buf, int k0) {
        #pragma unroll
        for (int i = 0; i < 2; ++i) {
            int slot = i * 256 + tid;
            int r = slot >> 2;
            int j = slot & 3;
            int js = j ^ ((r >> 1) & 3);
            size_t go = (size_t)r * K + k0 + js * 8;
            int lo = i * 2048 + wid * 512;
            gload_lds16(Ag + go, &lds[buf][0][lo]);
            gload_lds16(Bg + go, &lds[buf][1][lo]);
        }
    };

    f32x4 acc[4][4];
    #pragma unroll
    for (int a_ = 0; a_ < 4; ++a_)
        #pragma unroll
        for (int b_ = 0; b_ < 4; ++b_) acc[a_][b_] = (f32x4){0.f, 0.f, 0.f, 0.f};

    const int wm = wid >> 1, wn = wid & 1;
    stage(0, 0);
    __syncthreads();
    int nk = K >> 5;
    int buf = 0;
    for (int kt = 0; kt < nk; ++kt) {
        if (kt + 1 < nk) stage(buf ^ 1, (kt + 1) << 5);
        s16x8 af[4], bf_[4];
        #pragma unroll
        for (int mt = 0; mt < 4; ++mt) {
            int r = wm * 64 + mt * 16 + t16;
            af[mt] = *(const s16x8*)&lds[buf][0][r * 32 + ((g ^ ((r >> 1) & 3)) << 3)];
        }
        #pragma unroll
        for (int nt_ = 0; nt_ < 4; ++nt_) {
            int r = wn * 64 + nt_ * 16 + t16;
            bf_[nt_] = *(const s16x8*)&lds[buf][1][r * 32 + ((g ^ ((r >> 1) & 3)) << 3)];
        }
        #pragma unroll
        for (int mt = 0; mt < 4; ++mt)
            #pragma unroll
            for (int nt_ = 0; nt_ < 4; ++nt_)
                acc[mt][nt_] = mfma_bf16(af[mt], bf_[nt_], acc[mt][nt_]);
        __syncthreads();
        buf ^= 1;
    }

    #pragma unroll
    for (int mt = 0; mt < 4; ++mt)
        #pragma unroll
        for (int nt_ = 0; nt_ < 4; ++nt_) {
            int row0 = bm * 128 + wm * 64 + mt * 16 + g * 4;
            int col  = bn * 128 + wn * 64 + nt_ * 16 + t16;
            f32x4 v = acc[mt][nt_];
            float bv = (EPI == 2) ? bias[col] : 0.0f;
            #pragma unroll
            for (int r_ = 0; r_ < 4; ++r_) {
                size_t idx = (size_t)(row0 + r_) * N + col;
                if (EPI == 0) {
                    ob[idx] = f2bf(v[r_]);
                } else {
                    float tv = v[r_] + bv;
                    float ge = 0.5f * tv * (1.0f + erff(tv * 0.70710678118f));
                    ob[idx] = f2bf(ge);
                }
            }
        }
}

// ---- deep-pipelined GEMM for W2 (K=2048) ----
__global__ __launch_bounds__(512, 2) void k_gemm8(
    const unsigned short* __restrict__ A, const unsigned short* __restrict__ Bt,
    unsigned short* __restrict__ ob,
    const float* __restrict__ bias, int N, int K, int nt)
{
    extern __shared__ short lds[];           // 3 * 24576 shorts = 144KB
    const int tid = threadIdx.x;
    const int lane = tid & 63;
    const int wid = tid >> 6;
    const int g = lane >> 4;
    const int t16 = lane & 15;
    const int wm = wid >> 2, wn = wid & 3;

    int nwg = gridDim.x;
    int bid = blockIdx.x;
    int cpx = nwg >> 3;
    int swz = (bid & 7) * cpx + (bid >> 3);
    int bm = swz / nt;
    int bn = swz - bm * nt;

    const unsigned short* Ag = A  + (size_t)bm * 256 * K;
    const unsigned short* Bg = Bt + (size_t)bn * 128 * K;

    auto stage_unit = [&](int slot, int t, int unit) {
        const int k0 = t << 6;
        const unsigned short* src = (unit == 2) ? Bg : (Ag + (unit ? (size_t)128 * K : 0));
        short* dst0 = lds + slot * 24576 + (unit == 2 ? 16384 : unit * 8192);
        #pragma unroll
        for (int rr = 0; rr < 2; ++rr) {
            int rb = rr * 64 + wid * 8;
            int r_in = rb + (lane >> 3);
            int c = (lane & 7) ^ (r_in & 7);
            gload_lds16(src + (size_t)r_in * K + k0 + c * 8, dst0 + rb * 64);
        }
    };

    f32x4 acc[8][2];
    #pragma unroll
    for (int a_ = 0; a_ < 8; ++a_)
        #pragma unroll
        for (int b_ = 0; b_ < 2; ++b_) acc[a_][b_] = (f32x4){0.f, 0.f, 0.f, 0.f};

    const int nk = K >> 6;
    stage_unit(0, 0, 0); stage_unit(0, 0, 1); stage_unit(0, 0, 2);
    stage_unit(1, 1, 0); stage_unit(1, 1, 1); stage_unit(1, 1, 2);

    int slot = 0;
    for (int t = 0; t < nk; ++t) {
        if (t + 1 < nk) asm volatile("s_waitcnt vmcnt(6)" ::: "memory");
        else            asm volatile("s_waitcnt vmcnt(0)" ::: "memory");
        __builtin_amdgcn_s_barrier();
        __builtin_amdgcn_sched_barrier(0);

        int s2 = slot + 2; if (s2 >= 3) s2 -= 3;
        const short* As = lds + slot * 24576;
        const short* Bs = As + 16384;

        if (t + 2 < nk) { stage_unit(s2, t + 2, 0); stage_unit(s2, t + 2, 1); }
        s16x8 bfr[2][2];
        #pragma unroll
        for (int nn = 0; nn < 2; ++nn) {
            int row = wn * 32 + nn * 16 + t16;
            #pragma unroll
            for (int kk = 0; kk < 2; ++kk)
                bfr[nn][kk] = *(const s16x8*)&Bs[row * 64 + (((kk * 4 + g) ^ (row & 7)) << 3)];
        }
        {
            s16x8 afr[4][2];
            #pragma unroll
            for (int mm = 0; mm < 4; ++mm) {
                int row = wm * 128 + mm * 16 + t16;
                #pragma unroll
                for (int kk = 0; kk < 2; ++kk)
                    afr[mm][kk] = *(const s16x8*)&As[row * 64 + (((kk * 4 + g) ^ (row & 7)) << 3)];
            }
            __builtin_amdgcn_sched_barrier(0);
            __builtin_amdgcn_s_setprio(1);
            #pragma unroll
            for (int mm = 0; mm < 4; ++mm)
                #pragma unroll
                for (int nn = 0; nn < 2; ++nn)
                    #pragma unroll
                    for (int kk = 0; kk < 2; ++kk)
                        acc[mm][nn] = mfma_bf16(afr[mm][kk], bfr[nn][kk], acc[mm][nn]);
            __builtin_amdgcn_s_setprio(0);
            __builtin_amdgcn_sched_barrier(0);
        }
        if (t + 2 < nk) stage_unit(s2, t + 2, 2);
        {
            s16x8 afr[4][2];
            #pragma unroll
            for (int mm = 0; mm < 4; ++mm) {
                int row = wm * 128 + (mm + 4) * 16 + t16;
                #pragma unroll
                for (int kk = 0; kk < 2; ++kk)
                    afr[mm][kk] = *(const s16x8*)&As[row * 64 + (((kk * 4 + g) ^ (row & 7)) << 3)];
            }
            __builtin_amdgcn_sched_barrier(0);
            __builtin_amdgcn_s_setprio(1);
            #pragma unroll
            for (int mm = 0; mm < 4; ++mm)
                #pragma unroll
                for (int nn = 0; nn < 2; ++nn)
                    #pragma unroll
                    for (int kk = 0; kk < 2; ++kk)
                        acc[mm + 4][nn] = mfma_bf16(afr[mm][kk], bfr[nn][kk], acc[mm + 4][nn]);
            __builtin_amdgcn_s_setprio(0);
            __builtin_amdgcn_sched_barrier(0);
        }
        slot = slot + 1 == 3 ? 0 : slot + 1;
    }

    #pragma unroll
    for (int mm = 0; mm < 8; ++mm)
        #pragma unroll
        for (int nn = 0; nn < 2; ++nn) {
            int row0 = bm * 256 + wm * 128 + mm * 16 + g * 4;
            int col  = bn * 128 + wn * 32 + nn * 16 + t16;
            f32x4 v = acc[mm][nn];
            float bv = bias[col];
            #pragma unroll
            for (int r_ = 0; r_ < 4; ++r_)
                ob[(size_t)(row0 + r_) * N + col] = f2bf(v[r_] + bv);
        }
}

// ---- attention quarter-split: block = (b,h,qh,kh); 8 waves, 80KB LDS,
// 2 blocks/CU. Writes unnormalized bf16 partials + f32 (m,l) per row.
__global__ __launch_bounds__(512, 4) void k_attn(
    const unsigned short* __restrict__ qkv, const int* __restrict__ mask,
    unsigned short* __restrict__ op, float* __restrict__ mbuf,
    float* __restrict__ lbuf)
{
    extern __shared__ short smem[];
    short* Kl = smem;                        // [256][64], swizzled
    short* Vl = smem + 16384;                // [64][256], swizzled
    const int tid = threadIdx.x;
    const int lane = tid & 63, wid = tid >> 6;     // 8 waves
    short* Pl = smem + 32768 + wid * 1024;   // per-wave [16][64]
    const int kh = blockIdx.x & 1;
    const int qh = (blockIdx.x >> 1) & 1;
    const int h  = (blockIdx.x >> 2) & 7;
    const int b  = blockIdx.x >> 5;
    const unsigned short* base = qkv + (size_t)b * SS * 1536;
    const int qc = h * 64, kc = 512 + h * 64, vc = 1024 + h * 64;
    const int k0g = kh * 256;                // global key offset

    // stage K quarter via async global->LDS (linear dest, pre-swizzled src)
    {
        int row0 = tid >> 3;                 // 0..63
        int s = tid & 7;
        #pragma unroll
        for (int it = 0; it < 4; ++it) {
            int row = it * 64 + row0;        // local 0..255
            int j = s ^ (row & 7);
            gload_lds16(base + (size_t)(k0g + row) * 1536 + kc + j * 8,
                        Kl + it * 4096 + wid * 512);
        }
    }
    // stage V^T quarter via register 8x8 transpose
    {
        int unit = tid >> 1, half = tid & 1; // unit 0..255
        int t0 = (unit >> 3) << 3;           // local 0..248
        int e0 = (unit & 7) << 3;
        s16x8 r0 = *(const s16x8*)(base + (size_t)(k0g + t0 + half*4 + 0) * 1536 + vc + e0);
        s16x8 r1 = *(const s16x8*)(base + (size_t)(k0g + t0 + half*4 + 1) * 1536 + vc + e0);
        s16x8 r2 = *(const s16x8*)(base + (size_t)(k0g + t0 + half*4 + 2) * 1536 + vc + e0);
        s16x8 r3 = *(const s16x8*)(base + (size_t)(k0g + t0 + half*4 + 3) * 1536 + vc + e0);
        #pragma unroll
        for (int j = 0; j < 8; ++j) {
            int e = e0 + j;
            int slot = (t0 >> 3) ^ (e & 7) ^ ((e >> 3) & 7);
            s16x4 w = (s16x4){r0[j], r1[j], r2[j], r3[j]};
            *(s16x4*)(Vl + e * 256 + (slot << 3) + (half << 2)) = w;
        }
    }
    const int g = lane >> 4, t16 = lane & 15;
    unsigned mbits = 0;
    for (int n2 = 0; n2 < 16; ++n2)
        if (mask[b * SS + k0g + n2 * 16 + t16] != 0) mbits |= (1u << n2);
    __syncthreads();

    for (int qi = 0; qi < 2; ++qi) {
        const int q0 = qh * 256 + (wid * 2 + qi) * 16;
        s16x8 aq[2];
        #pragma unroll
        for (int ks = 0; ks < 2; ++ks)
            aq[ks] = *(const s16x8*)(base + (size_t)(q0 + t16) * 1536 + qc + ks * 32 + g * 8);

        f32x4 oacc[4];
        #pragma unroll
        for (int eo = 0; eo < 4; ++eo) oacc[eo] = (f32x4){0.f, 0.f, 0.f, 0.f};
        float mx[4] = {-3.0e38f, -3.0e38f, -3.0e38f, -3.0e38f};
        float ls[4] = {0.f, 0.f, 0.f, 0.f};

        for (int tc = 0; tc < 2; ++tc) {     // 2 x 128-key chunks (local)
            f32x4 s[8];
            #pragma unroll
            for (int n2 = 0; n2 < 8; ++n2) s[n2] = (f32x4){0.f, 0.f, 0.f, 0.f};
            #pragma unroll
            for (int n2 = 0; n2 < 8; ++n2) {
                int t = tc * 128 + n2 * 16 + t16;          // local key
                #pragma unroll
                for (int ks = 0; ks < 2; ++ks) {
                    int blk = ks * 4 + g;
                    s16x8 bk = *(const s16x8*)(Kl + t * 64 + ((blk ^ (t & 7)) << 3));
                    s[n2] = mfma_bf16(aq[ks], bk, s[n2]);
                }
            }
            #pragma unroll
            for (int n2 = 0; n2 < 8; ++n2) {
                bool val = (mbits >> (tc * 8 + n2)) & 1u;
                #pragma unroll
                for (int r_ = 0; r_ < 4; ++r_)
                    s[n2][r_] = val ? s[n2][r_] : -3.0e38f;
            }
            float sc[4];
            #pragma unroll
            for (int r_ = 0; r_ < 4; ++r_) {
                float m = s[0][r_];
                #pragma unroll
                for (int n2 = 1; n2 < 8; ++n2) m = fmaxf(m, s[n2][r_]);
                #pragma unroll
                for (int off = 1; off < 16; off <<= 1) m = fmaxf(m, __shfl_xor(m, off));
                float mn = fmaxf(mx[r_], m);
                sc[r_] = exp2_fast(mx[r_] - mn);
                mx[r_] = mn;
                ls[r_] *= sc[r_];
            }
            #pragma unroll
            for (int eo = 0; eo < 4; ++eo)
                #pragma unroll
                for (int r_ = 0; r_ < 4; ++r_) oacc[eo][r_] *= sc[r_];
            #pragma unroll
            for (int n2 = 0; n2 < 8; ++n2)
                #pragma unroll
                for (int r_ = 0; r_ < 4; ++r_)
                    s[n2][r_] = exp2_fast(s[n2][r_] - mx[r_]);
            #pragma unroll
            for (int r_ = 0; r_ < 4; ++r_) {
                float t = 0.f;
                #pragma unroll
                for (int n2 = 0; n2 < 8; ++n2) t += s[n2][r_];
                #pragma unroll
                for (int off = 1; off < 16; off <<= 1) t += __shfl_xor(t, off);
                ls[r_] += t;
            }
            #pragma unroll
            for (int c4 = 0; c4 < 2; ++c4) {
                #pragma unroll
                for (int k4 = 0; k4 < 4; ++k4) {
                    int n2 = c4 * 4 + k4;
                    #pragma unroll
                    for (int r_ = 0; r_ < 4; ++r_) {
                        int qq = g * 4 + r_;
                        int kk = k4 * 16 + t16;
                        Pl[qq * 64 + (((kk >> 3) ^ (qq & 7)) << 3) + (kk & 7)] =
                            (short)f2bf(s[n2][r_]);
                    }
                }
                #pragma unroll
                for (int ks2 = 0; ks2 < 2; ++ks2) {
                    int kk = ks2 * 32 + g * 8;
                    s16x8 pa = *(const s16x8*)(Pl + t16 * 64 + (((kk >> 3) ^ (t16 & 7)) << 3));
                    int tg = tc * 128 + c4 * 64 + kk;      // local key base
                    #pragma unroll
                    for (int eo = 0; eo < 4; ++eo) {
                        int e = eo * 16 + t16;
                        int slot = (tg >> 3) ^ (e & 7) ^ ((e >> 3) & 7);
                        s16x8 bv = *(const s16x8*)(Vl + e * 256 + (slot << 3));
                        oacc[eo] = mfma_bf16(pa, bv, oacc[eo]);
                    }
                }
            }
        }
        // write unnormalized partial (bf16) + per-row m,l (f32)
        #pragma unroll
        for (int eo = 0; eo < 4; ++eo)
            #pragma unroll
            for (int r_ = 0; r_ < 4; ++r_) {
                int row = q0 + g * 4 + r_;
                int e = eo * 16 + t16;
                op[(size_t)kh * MM * DD + ((size_t)b * SS + row) * DD + h * HDH + e] =
                    f2bf(oacc[eo][r_]);
            }
        if (t16 == 0) {
            #pragma unroll
            for (int r_ = 0; r_ < 4; ++r_) {
                int row = q0 + g * 4 + r_;
                size_t u = (size_t)kh * MM * HH + ((size_t)b * SS + row) * HH + h;
                mbuf[u] = mx[r_];
                lbuf[u] = ls[r_];
            }
        }
    }
}

// ---- flash-merge of the two kv-half partials ----
__global__ __launch_bounds__(256) void k_attn_merge(
    const unsigned short* __restrict__ op, const float* __restrict__ mbuf,
    const float* __restrict__ lbuf, unsigned short* __restrict__ o)
{
    int i = blockIdx.x * 256 + threadIdx.x;  // over MM*HH*16 e-quads
    int eq = i & 15;
    int unit = i >> 4;                       // (b*SS+row)*HH + h
    int h = unit & 7;
    int brow = unit >> 3;
    float m0 = mbuf[unit], m1 = mbuf[MM * HH + unit];
    float l0 = lbuf[unit], l1 = lbuf[MM * HH + unit];
    float ms = fmaxf(m0, m1);
    float w0 = exp2_fast(m0 - ms);
    float w1 = exp2_fast(m1 - ms);
    float inv = 1.0f / (l0 * w0 + l1 * w1);
    w0 *= inv; w1 *= inv;
    size_t off = (size_t)brow * DD + h * HDH + eq * 4;
    s16x4 a = *(const s16x4*)(op + off);
    s16x4 c = *(const s16x4*)(op + (size_t)MM * DD + off);
    s16x4 r;
    #pragma unroll
    for (int j = 0; j < 4; ++j)
        r[j] = (short)f2bf(bf2f((unsigned short)a[j]) * w0 +
                           bf2f((unsigned short)c[j]) * w1);
    *(s16x4*)(o + off) = r;
}

extern "C" void kernel_launch(void* const* d_in, const int* in_sizes, int n_in,
                              void* d_out, int out_size, void* d_ws, size_t ws_size,
                              hipStream_t stream)
{
    const int*   tokens = (const int*)d_in[0];
    const int*   mask   = (const int*)d_in[1];
    const float* emb    = (const float*)d_in[2];
    const float* pe     = (const float*)d_in[3];
    const float* Wq     = (const float*)d_in[4];
    const float* Wk     = (const float*)d_in[5];
    const float* Wv     = (const float*)d_in[6];
    const float* Wo     = (const float*)d_in[7];
    const float* l1g    = (const float*)d_in[8];
    const float* l1b    = (const float*)d_in[9];
    const float* W1     = (const float*)d_in[10];
    const float* b1     = (const float*)d_in[11];
    const float* W2     = (const float*)d_in[12];
    const float* b2     = (const float*)d_in[13];
    const float* l2g    = (const float*)d_in[14];
    const float* l2b    = (const float*)d_in[15];

    char* p = (char*)d_ws;
    auto alloc = [&](size_t bytes) { char* r = p; p += (bytes + 255) & ~(size_t)255; return r; };
    unsigned short* wqkv_t = (unsigned short*)alloc((size_t)LL*3*DD*DD*2);
    unsigned short* wo_t   = (unsigned short*)alloc((size_t)LL*DD*DD*2);
    unsigned short* w1_t   = (unsigned short*)alloc((size_t)LL*DD*DFF*2);
    unsigned short* w2_t   = (unsigned short*)alloc((size_t)LL*DD*DFF*2);
    unsigned short* xh     = (unsigned short*)alloc((size_t)MM*DD*2);
    unsigned short* xl     = (unsigned short*)alloc((size_t)MM*DD*2);
    unsigned short* qkvb   = (unsigned short*)alloc((size_t)MM*1536*2);
    unsigned short* obuf   = (unsigned short*)alloc((size_t)MM*DD*2);
    unsigned short* ybufb  = (unsigned short*)alloc((size_t)MM*DD*2);
    unsigned short* opart  = (unsigned short*)alloc((size_t)2*MM*DD*2);
    float*          mbuf   = (float*)alloc((size_t)2*MM*HH*4);
    float*          lbuf   = (float*)alloc((size_t)2*MM*HH*4);
    unsigned short* hbuf   = qkvb;   // [MM][2048] aliases qkvb+obuf (dead then)

    k_tconv_all<<<4608, 256, 0, stream>>>(Wq, Wk, Wv, Wo, W1, W2,
                                          wqkv_t, wo_t, w1_t, w2_t);
    k_embed<<<8192, 256, 0, stream>>>(tokens, emb, pe, xh, xl);

    hipFuncSetAttribute((const void*)k_attn,
                        hipFuncAttributeMaxDynamicSharedMemorySize, 81920);
    hipFuncSetAttribute((const void*)k_gemm8,
                        hipFuncAttributeMaxDynamicSharedMemorySize, 147456);

    for (int l = 0; l < LL; ++l) {
        const unsigned short* wqkvl = wqkv_t + (size_t)l*3*DD*DD;
        const unsigned short* wol   = wo_t   + (size_t)l*DD*DD;
        const unsigned short* w1l   = w1_t   + (size_t)l*DD*DFF;
        const unsigned short* w2l   = w2_t   + (size_t)l*DD*DFF;

        k_gemm<0><<<1536, 256, 0, stream>>>(xh, wqkvl, qkvb, nullptr, 1536, 512, 12);
        k_attn<<<1024, 512, 81920, stream>>>(qkvb, mask, opart, mbuf, lbuf);
        k_attn_merge<<<8192, 256, 0, stream>>>(opart, mbuf, lbuf, obuf);
        k_gemm<0><<<512, 256, 0, stream>>>(obuf, wol, ybufb, nullptr, 512, 512, 4);
        k_ln<<<16384, 128, 0, stream>>>(xh, xl, ybufb, l1g + l*DD, l1b + l*DD, nullptr);
        k_gemm<2><<<2048, 256, 0, stream>>>(xh, w1l, hbuf, b1 + (size_t)l*DFF, 2048, 512, 16);
        k_gemm8<<<256, 512, 147456, stream>>>(hbuf, w2l, ybufb, b2 + (size_t)l*DD, 512, 2048, 4);
        float* xout = (l == LL - 1) ? (float*)d_out : nullptr;
        k_ln<<<16384, 128, 0, stream>>>(xh, xl, ybufb, l2g + l*DD, l2b + l*DD, xout);
    }
}

// Round 14
// 1334.403 us; speedup vs baseline: 1.0636x; 1.0636x over previous
//
// EncoderModel forward, MI355X/gfx950. Round 14: revert to round-12 best
// (1338us). Quarter-split attention (round 13) regressed: partial-merge
// traffic + extra dispatch outweighed the occupancy gain. This is the
// session-best configuration:
// - GEMMs: proven 2-phase 128x128 bf16 MFMA (QKV fused N=1536; W1 gelu-fused)
// - W2: 3-slot-ring deep-pipelined BM=256 kernel (K=2048)
// - attention: 1 block/(b,h), 16 waves, flash over 128-key chunks, async-K
//   global_load_lds staging, exp2-domain softmax (0.125*log2e folded into Wk)
// - residual: hi/lo bf16 split (f32-exact to ~2^-17, half the LN traffic)
// - single merged weight-conversion dispatch (LDS-tiled transposes)
#include <hip/hip_runtime.h>

#define BB 32
#define SS 512
#define DD 512
#define HH 8
#define HDH 64
#define LL 6
#define DFF 2048
#define MM (BB*SS)

typedef __attribute__((ext_vector_type(4))) float f32x4;
typedef __attribute__((ext_vector_type(8))) short s16x8;
typedef __attribute__((ext_vector_type(4))) short s16x4;

__device__ __forceinline__ unsigned short f2bf(float f) {
    union { float f; unsigned u; } v; v.f = f;
    unsigned r = v.u + 0x7fffu + ((v.u >> 16) & 1u);
    return (unsigned short)(r >> 16);
}
__device__ __forceinline__ float bf2f(unsigned short b) {
    union { unsigned u; float f; } v; v.u = ((unsigned)b) << 16;
    return v.f;
}
__device__ __forceinline__ float exp2_fast(float x) {
    float r; asm("v_exp_f32 %0, %1" : "=v"(r) : "v"(x)); return r;
}

__device__ __forceinline__ f32x4 mfma_bf16(s16x8 a, s16x8 b, f32x4 c) {
    asm("v_mfma_f32_16x16x32_bf16 %0, %1, %2, %0" : "+v"(c) : "v"(a), "v"(b));
    return c;
}

__device__ __forceinline__ void gload_lds16(const void* g, void* l) {
    __builtin_amdgcn_global_load_lds(
        (__attribute__((address_space(1))) void*)g,
        (__attribute__((address_space(3))) void*)l, 16, 0, 0);
}

// ---- LDS 64x64 tile transpose-convert: f32 [K][N] tile -> bf16 [N][K] -----
__device__ __forceinline__ void tile_transpose_conv(
    const float* __restrict__ src, int srcPitch,
    unsigned short* __restrict__ dst, int dstPitch,
    float* lt, float scale)
{
    const int t = threadIdx.x;
    #pragma unroll
    for (int it = 0; it < 4; ++it) {
        int r = it * 16 + (t >> 4);
        int c = (t & 15) * 4;
        f32x4 v = *(const f32x4*)(src + (size_t)r * srcPitch + c);
        lt[r * 65 + c + 0] = v[0];
        lt[r * 65 + c + 1] = v[1];
        lt[r * 65 + c + 2] = v[2];
        lt[r * 65 + c + 3] = v[3];
    }
    __syncthreads();
    int nn = t >> 2;
    int kc = (t & 3) * 16;
    s16x8 o0, o1;
    #pragma unroll
    for (int i = 0; i < 8; ++i)  o0[i] = (short)f2bf(lt[(kc + i) * 65 + nn] * scale);
    #pragma unroll
    for (int i = 0; i < 8; ++i)  o1[i] = (short)f2bf(lt[(kc + 8 + i) * 65 + nn] * scale);
    *(s16x8*)(dst + (size_t)nn * dstPitch + kc) = o0;
    *(s16x8*)(dst + (size_t)nn * dstPitch + kc + 8) = o1;
}

// Merged weight conversion (one dispatch)
__global__ __launch_bounds__(256) void k_tconv_all(
    const float* __restrict__ Wq, const float* __restrict__ Wk,
    const float* __restrict__ Wv, const float* __restrict__ Wo,
    const float* __restrict__ W1, const float* __restrict__ W2,
    unsigned short* __restrict__ wqkv_t, unsigned short* __restrict__ wo_t,
    unsigned short* __restrict__ w1_t, unsigned short* __restrict__ w2_t)
{
    __shared__ float lt[64 * 65];
    int bid = blockIdx.x;
    if (bid < 1152) {
        int which = bid / 384;
        int rem = bid - which * 384;
        int l = rem >> 6;
        int h = (rem >> 3) & 7;
        int kt = rem & 7;
        const float* W = which == 0 ? Wq : (which == 1 ? Wk : Wv);
        float scale = (which == 1) ? 0.18033688011116048f : 1.0f;  // 0.125*log2(e)
        const float* srcT = W + (((size_t)(l * HH + h) * 512) + kt * 64) * 64;
        unsigned short* dstT = wqkv_t + ((size_t)l * 1536 + which * 512 + h * 64) * 512 + kt * 64;
        tile_transpose_conv(srcT, 64, dstT, 512, lt, scale);
        return;
    }
    const float* src; unsigned short* dst; int K, N, rem;
    if (bid < 1536)      { src = Wo; dst = wo_t; K = 512;  N = 512;  rem = bid - 1152; }
    else if (bid < 3072) { src = W1; dst = w1_t; K = 512;  N = 2048; rem = bid - 1536; }
    else                 { src = W2; dst = w2_t; K = 2048; N = 512;  rem = bid - 3072; }
    int tpb = (K >> 6) * (N >> 6);
    int l = rem / tpb;
    int r2 = rem - l * tpb;
    int kt = r2 / (N >> 6);
    int ntile = r2 - kt * (N >> 6);
    const float* srcT = src + (size_t)l * K * N + (size_t)(kt * 64) * N + ntile * 64;
    unsigned short* dstT = dst + (size_t)l * N * K + (size_t)(ntile * 64) * K + kt * 64;
    tile_transpose_conv(srcT, N, dstT, K, lt, 1.0f);
}

// ---- embedding + positional encoding -> hi/lo bf16 pair ----
__global__ __launch_bounds__(256) void k_embed(const int* __restrict__ tokens,
                                               const float* __restrict__ emb,
                                               const float* __restrict__ pe,
                                               unsigned short* __restrict__ xh,
                                               unsigned short* __restrict__ xl) {
    int i = blockIdx.x * 256 + threadIdx.x;
    int row = i >> 7;
    int d4 = (i & 127) * 4;
    int srow = row & (SS - 1);
    int tok = tokens[row];
    f32x4 ev = *(const f32x4*)(emb + (size_t)tok*DD + d4);
    f32x4 pv = *(const f32x4*)(pe + (size_t)srow*DD + d4);
    s16x4 hv, lv;
    #pragma unroll
    for (int j = 0; j < 4; ++j) {
        float v = ev[j] + pv[j];
        unsigned short hi = f2bf(v);
        hv[j] = (short)hi;
        lv[j] = (short)f2bf(v - bf2f(hi));
    }
    *(s16x4*)(xh + (size_t)row*DD + d4) = hv;
    *(s16x4*)(xl + (size_t)row*DD + d4) = lv;
}

// ---- fused residual + layernorm; residual = (xh,xl) bf16 pair, y bf16 ----
__global__ __launch_bounds__(128) void k_ln(unsigned short* xh,
                                            unsigned short* xl,
                                            const unsigned short* __restrict__ y,
                                            const float* __restrict__ gg,
                                            const float* __restrict__ bb,
                                            float* __restrict__ xo) {
    const int row = blockIdx.x;
    const int tid = threadIdx.x;
    __shared__ float red[4];
    s16x4 hv0 = *(const s16x4*)(xh + (size_t)row*DD + tid*4);
    s16x4 lv0 = *(const s16x4*)(xl + (size_t)row*DD + tid*4);
    s16x4 yv = *(const s16x4*)(y + (size_t)row*DD + tid*4);
    f32x4 vv;
    #pragma unroll
    for (int j = 0; j < 4; ++j)
        vv[j] = (bf2f((unsigned short)hv0[j]) + bf2f((unsigned short)lv0[j]))
                + bf2f((unsigned short)yv[j]);
    float sum = vv[0] + vv[1] + vv[2] + vv[3];
    #pragma unroll
    for (int off = 1; off < 64; off <<= 1) sum += __shfl_xor(sum, off);
    if ((tid & 63) == 0) red[tid >> 6] = sum;
    __syncthreads();
    float mu = (red[0] + red[1]) * (1.0f / 512.0f);
    float s2 = 0.0f;
    #pragma unroll
    for (int j = 0; j < 4; ++j) { float d = vv[j] - mu; s2 += d * d; }
    #pragma unroll
    for (int off = 1; off < 64; off <<= 1) s2 += __shfl_xor(s2, off);
    if ((tid & 63) == 0) red[2 + (tid >> 6)] = s2;
    __syncthreads();
    float var = (red[2] + red[3]) * (1.0f / 512.0f);
    float rs = rsqrtf(var + 1e-5f);
    f32x4 gv = *(const f32x4*)(gg + tid*4);
    f32x4 bv = *(const f32x4*)(bb + tid*4);
    s16x4 hv, lv;
    f32x4 ov;
    #pragma unroll
    for (int j = 0; j < 4; ++j) {
        float o = (vv[j] - mu) * rs * gv[j] + bv[j];
        ov[j] = o;
        unsigned short hi = f2bf(o);
        hv[j] = (short)hi;
        lv[j] = (short)f2bf(o - bf2f(hi));
    }
    *(s16x4*)(xh + (size_t)row*DD + tid*4) = hv;
    *(s16x4*)(xl + (size_t)row*DD + tid*4) = lv;
    if (xo) *(f32x4*)(xo + (size_t)row*DD + tid*4) = ov;
}

// ---- GEMM (2-phase 128x128, proven): C = A @ Bt^T ----
// EPI: 0 = bf16 out, 2 = bf16 gelu(out+bias)
template<int EPI>
__global__ __launch_bounds__(256, 2) void k_gemm(
    const unsigned short* __restrict__ A, const unsigned short* __restrict__ Bt,
    unsigned short* __restrict__ ob,
    const float* __restrict__ bias, int N, int K, int nt)
{
    __shared__ short lds[2][2][4096];
    const int tid = threadIdx.x;
    const int lane = tid & 63;
    const int wid = tid >> 6;
    const int g = lane >> 4;
    const int t16 = lane & 15;

    int nwg = gridDim.x;
    int bid = blockIdx.x;
    int cpx = nwg >> 3;
    int swz = (bid & 7) * cpx + (bid >> 3);
    int bm = swz / nt;
    int bn = swz - bm * nt;

    const unsigned short* Ag = A  + (size_t)bm * 128 * K;
    const unsigned short* Bg = Bt + (size_t)bn * 128 * K;

    auto stage = [&](int buf, int k0) {
        #pragma unroll
        for (int i = 0; i < 2; ++i) {
            int slot = i * 256 + tid;
            int r = slot >> 2;
            int j = slot & 3;
            int js = j ^ ((r >> 1) & 3);
            size_t go = (size_t)r * K + k0 + js * 8;
            int lo = i * 2048 + wid * 512;
            gload_lds16(Ag + go, &lds[buf][0][lo]);
            gload_lds16(Bg + go, &lds[buf][1][lo]);
        }
    };

    f32x4 acc[4][4];
    #pragma unroll
    for (int a_ = 0; a_ < 4; ++a_)
        #pragma unroll
        for (int b_ = 0; b_ < 4; ++b_) acc[a_][b_] = (f32x4){0.f, 0.f, 0.f, 0.f};

    const int wm = wid >> 1, wn = wid & 1;
    stage(0, 0);
    __syncthreads();
    int nk = K >> 5;
    int buf = 0;
    for (int kt = 0; kt < nk; ++kt) {
        if (kt + 1 < nk) stage(buf ^ 1, (kt + 1) << 5);
        s16x8 af[4], bf_[4];
        #pragma unroll
        for (int mt = 0; mt < 4; ++mt) {
            int r = wm * 64 + mt * 16 + t16;
            af[mt] = *(const s16x8*)&lds[buf][0][r * 32 + ((g ^ ((r >> 1) & 3)) << 3)];
        }
        #pragma unroll
        for (int nt_ = 0; nt_ < 4; ++nt_) {
            int r = wn * 64 + nt_ * 16 + t16;
            bf_[nt_] = *(const s16x8*)&lds[buf][1][r * 32 + ((g ^ ((r >> 1) & 3)) << 3)];
        }
        #pragma unroll
        for (int mt = 0; mt < 4; ++mt)
            #pragma unroll
            for (int nt_ = 0; nt_ < 4; ++nt_)
                acc[mt][nt_] = mfma_bf16(af[mt], bf_[nt_], acc[mt][nt_]);
        __syncthreads();
        buf ^= 1;
    }

    #pragma unroll
    for (int mt = 0; mt < 4; ++mt)
        #pragma unroll
        for (int nt_ = 0; nt_ < 4; ++nt_) {
            int row0 = bm * 128 + wm * 64 + mt * 16 + g * 4;
            int col  = bn * 128 + wn * 64 + nt_ * 16 + t16;
            f32x4 v = acc[mt][nt_];
            float bv = (EPI == 2) ? bias[col] : 0.0f;
            #pragma unroll
            for (int r_ = 0; r_ < 4; ++r_) {
                size_t idx = (size_t)(row0 + r_) * N + col;
                if (EPI == 0) {
                    ob[idx] = f2bf(v[r_]);
                } else {
                    float tv = v[r_] + bv;
                    float ge = 0.5f * tv * (1.0f + erff(tv * 0.70710678118f));
                    ob[idx] = f2bf(ge);
                }
            }
        }
}

// ---- deep-pipelined GEMM for W2 (K=2048) ----
__global__ __launch_bounds__(512, 2) void k_gemm8(
    const unsigned short* __restrict__ A, const unsigned short* __restrict__ Bt,
    unsigned short* __restrict__ ob,
    const float* __restrict__ bias, int N, int K, int nt)
{
    extern __shared__ short lds[];           // 3 * 24576 shorts = 144KB
    const int tid = threadIdx.x;
    const int lane = tid & 63;
    const int wid = tid >> 6;
    const int g = lane >> 4;
    const int t16 = lane & 15;
    const int wm = wid >> 2, wn = wid & 3;

    int nwg = gridDim.x;
    int bid = blockIdx.x;
    int cpx = nwg >> 3;
    int swz = (bid & 7) * cpx + (bid >> 3);
    int bm = swz / nt;
    int bn = swz - bm * nt;

    const unsigned short* Ag = A  + (size_t)bm * 256 * K;
    const unsigned short* Bg = Bt + (size_t)bn * 128 * K;

    auto stage_unit = [&](int slot, int t, int unit) {
        const int k0 = t << 6;
        const unsigned short* src = (unit == 2) ? Bg : (Ag + (unit ? (size_t)128 * K : 0));
        short* dst0 = lds + slot * 24576 + (unit == 2 ? 16384 : unit * 8192);
        #pragma unroll
        for (int rr = 0; rr < 2; ++rr) {
            int rb = rr * 64 + wid * 8;
            int r_in = rb + (lane >> 3);
            int c = (lane & 7) ^ (r_in & 7);
            gload_lds16(src + (size_t)r_in * K + k0 + c * 8, dst0 + rb * 64);
        }
    };

    f32x4 acc[8][2];
    #pragma unroll
    for (int a_ = 0; a_ < 8; ++a_)
        #pragma unroll
        for (int b_ = 0; b_ < 2; ++b_) acc[a_][b_] = (f32x4){0.f, 0.f, 0.f, 0.f};

    const int nk = K >> 6;
    stage_unit(0, 0, 0); stage_unit(0, 0, 1); stage_unit(0, 0, 2);
    stage_unit(1, 1, 0); stage_unit(1, 1, 1); stage_unit(1, 1, 2);

    int slot = 0;
    for (int t = 0; t < nk; ++t) {
        if (t + 1 < nk) asm volatile("s_waitcnt vmcnt(6)" ::: "memory");
        else            asm volatile("s_waitcnt vmcnt(0)" ::: "memory");
        __builtin_amdgcn_s_barrier();
        __builtin_amdgcn_sched_barrier(0);

        int s2 = slot + 2; if (s2 >= 3) s2 -= 3;
        const short* As = lds + slot * 24576;
        const short* Bs = As + 16384;

        if (t + 2 < nk) { stage_unit(s2, t + 2, 0); stage_unit(s2, t + 2, 1); }
        s16x8 bfr[2][2];
        #pragma unroll
        for (int nn = 0; nn < 2; ++nn) {
            int row = wn * 32 + nn * 16 + t16;
            #pragma unroll
            for (int kk = 0; kk < 2; ++kk)
                bfr[nn][kk] = *(const s16x8*)&Bs[row * 64 + (((kk * 4 + g) ^ (row & 7)) << 3)];
        }
        {
            s16x8 afr[4][2];
            #pragma unroll
            for (int mm = 0; mm < 4; ++mm) {
                int row = wm * 128 + mm * 16 + t16;
                #pragma unroll
                for (int kk = 0; kk < 2; ++kk)
                    afr[mm][kk] = *(const s16x8*)&As[row * 64 + (((kk * 4 + g) ^ (row & 7)) << 3)];
            }
            __builtin_amdgcn_sched_barrier(0);
            __builtin_amdgcn_s_setprio(1);
            #pragma unroll
            for (int mm = 0; mm < 4; ++mm)
                #pragma unroll
                for (int nn = 0; nn < 2; ++nn)
                    #pragma unroll
                    for (int kk = 0; kk < 2; ++kk)
                        acc[mm][nn] = mfma_bf16(afr[mm][kk], bfr[nn][kk], acc[mm][nn]);
            __builtin_amdgcn_s_setprio(0);
            __builtin_amdgcn_sched_barrier(0);
        }
        if (t + 2 < nk) stage_unit(s2, t + 2, 2);
        {
            s16x8 afr[4][2];
            #pragma unroll
            for (int mm = 0; mm < 4; ++mm) {
                int row = wm * 128 + (mm + 4) * 16 + t16;
                #pragma unroll
                for (int kk = 0; kk < 2; ++kk)
                    afr[mm][kk] = *(const s16x8*)&As[row * 64 + (((kk * 4 + g) ^ (row & 7)) << 3)];
            }
            __builtin_amdgcn_sched_barrier(0);
            __builtin_amdgcn_s_setprio(1);
            #pragma unroll
            for (int mm = 0; mm < 4; ++mm)
                #pragma unroll
                for (int nn = 0; nn < 2; ++nn)
                    #pragma unroll
                    for (int kk = 0; kk < 2; ++kk)
                        acc[mm + 4][nn] = mfma_bf16(afr[mm][kk], bfr[nn][kk], acc[mm + 4][nn]);
            __builtin_amdgcn_s_setprio(0);
            __builtin_amdgcn_sched_barrier(0);
        }
        slot = slot + 1 == 3 ? 0 : slot + 1;
    }

    #pragma unroll
    for (int mm = 0; mm < 8; ++mm)
        #pragma unroll
        for (int nn = 0; nn < 2; ++nn) {
            int row0 = bm * 256 + wm * 128 + mm * 16 + g * 4;
            int col  = bn * 128 + wn * 32 + nn * 16 + t16;
            f32x4 v = acc[mm][nn];
            float bv = bias[col];
            #pragma unroll
            for (int r_ = 0; r_ < 4; ++r_)
                ob[(size_t)(row0 + r_) * N + col] = f2bf(v[r_] + bv);
        }
}

// ---- attention: 1 block/(b,h), 16 waves, flash over 128-key chunks;
// K async-staged via global_load_lds; exp2-domain softmax.
__global__ __launch_bounds__(1024, 4) void k_attn(
    const unsigned short* __restrict__ qkv, const int* __restrict__ mask,
    unsigned short* __restrict__ o)
{
    extern __shared__ short smem[];
    short* Kl = smem;                        // [512][64], blk j ^= (t&7)
    short* Vl = smem + 32768;                // [64][512], blk ^= (e&7)^((e>>3)&7)
    const int tid = threadIdx.x;
    const int lane = tid & 63, wid = tid >> 6;
    short* Pl = smem + 65536 + wid * 1024;   // per-wave [16][64]
    const int b = blockIdx.x >> 3, h = blockIdx.x & 7;
    const unsigned short* base = qkv + (size_t)b * SS * 1536;
    const int qc = h * 64, kc = 512 + h * 64, vc = 1024 + h * 64;

    {
        int row0 = (tid >> 3);
        int s = tid & 7;
        #pragma unroll
        for (int it = 0; it < 4; ++it) {
            int row = it * 128 + row0;
            int j = s ^ (row & 7);
            gload_lds16(base + (size_t)row * 1536 + kc + j * 8,
                        Kl + it * 8192 + wid * 512);
        }
    }
    {
        int unit = tid >> 1, half = tid & 1;
        int t0 = (unit >> 3) << 3, e0 = (unit & 7) << 3;
        s16x8 r0 = *(const s16x8*)(base + (size_t)(t0 + half*4 + 0) * 1536 + vc + e0);
        s16x8 r1 = *(const s16x8*)(base + (size_t)(t0 + half*4 + 1) * 1536 + vc + e0);
        s16x8 r2 = *(const s16x8*)(base + (size_t)(t0 + half*4 + 2) * 1536 + vc + e0);
        s16x8 r3 = *(const s16x8*)(base + (size_t)(t0 + half*4 + 3) * 1536 + vc + e0);
        #pragma unroll
        for (int j = 0; j < 8; ++j) {
            int e = e0 + j;
            int slot = (t0 >> 3) ^ (e & 7) ^ ((e >> 3) & 7);
            s16x4 w = (s16x4){r0[j], r1[j], r2[j], r3[j]};
            *(s16x4*)(Vl + e * 512 + (slot << 3) + (half << 2)) = w;
        }
    }
    const int g = lane >> 4, t16 = lane & 15;
    unsigned mbits = 0;
    for (int n2 = 0; n2 < 32; ++n2)
        if (mask[b * SS + n2 * 16 + t16] != 0) mbits |= (1u << n2);
    __syncthreads();

    for (int qi = 0; qi < 2; ++qi) {
        const int q0 = (wid * 2 + qi) * 16;
        s16x8 aq[2];
        #pragma unroll
        for (int ks = 0; ks < 2; ++ks)
            aq[ks] = *(const s16x8*)(base + (size_t)(q0 + t16) * 1536 + qc + ks * 32 + g * 8);

        f32x4 oacc[4];
        #pragma unroll
        for (int eo = 0; eo < 4; ++eo) oacc[eo] = (f32x4){0.f, 0.f, 0.f, 0.f};
        float mx[4] = {-3.0e38f, -3.0e38f, -3.0e38f, -3.0e38f};
        float ls[4] = {0.f, 0.f, 0.f, 0.f};

        for (int tc = 0; tc < 4; ++tc) {
            f32x4 s[8];
            #pragma unroll
            for (int n2 = 0; n2 < 8; ++n2) s[n2] = (f32x4){0.f, 0.f, 0.f, 0.f};
            #pragma unroll
            for (int n2 = 0; n2 < 8; ++n2) {
                int t = tc * 128 + n2 * 16 + t16;
                #pragma unroll
                for (int ks = 0; ks < 2; ++ks) {
                    int blk = ks * 4 + g;
                    s16x8 bk = *(const s16x8*)(Kl + t * 64 + ((blk ^ (t & 7)) << 3));
                    s[n2] = mfma_bf16(aq[ks], bk, s[n2]);
                }
            }
            #pragma unroll
            for (int n2 = 0; n2 < 8; ++n2) {
                bool val = (mbits >> (tc * 8 + n2)) & 1u;
                #pragma unroll
                for (int r_ = 0; r_ < 4; ++r_)
                    s[n2][r_] = val ? s[n2][r_] : -3.0e38f;
            }
            float sc[4];
            #pragma unroll
            for (int r_ = 0; r_ < 4; ++r_) {
                float m = s[0][r_];
                #pragma unroll
                for (int n2 = 1; n2 < 8; ++n2) m = fmaxf(m, s[n2][r_]);
                #pragma unroll
                for (int off = 1; off < 16; off <<= 1) m = fmaxf(m, __shfl_xor(m, off));
                float mn = fmaxf(mx[r_], m);
                sc[r_] = exp2_fast(mx[r_] - mn);
                mx[r_] = mn;
                ls[r_] *= sc[r_];
            }
            #pragma unroll
            for (int eo = 0; eo < 4; ++eo)
                #pragma unroll
                for (int r_ = 0; r_ < 4; ++r_) oacc[eo][r_] *= sc[r_];
            #pragma unroll
            for (int n2 = 0; n2 < 8; ++n2)
                #pragma unroll
                for (int r_ = 0; r_ < 4; ++r_)
                    s[n2][r_] = exp2_fast(s[n2][r_] - mx[r_]);
            #pragma unroll
            for (int r_ = 0; r_ < 4; ++r_) {
                float t = 0.f;
                #pragma unroll
                for (int n2 = 0; n2 < 8; ++n2) t += s[n2][r_];
                #pragma unroll
                for (int off = 1; off < 16; off <<= 1) t += __shfl_xor(t, off);
                ls[r_] += t;
            }
            #pragma unroll
            for (int c4 = 0; c4 < 2; ++c4) {
                #pragma unroll
                for (int k4 = 0; k4 < 4; ++k4) {
                    int n2 = c4 * 4 + k4;
                    #pragma unroll
                    for (int r_ = 0; r_ < 4; ++r_) {
                        int qq = g * 4 + r_;
                        int kk = k4 * 16 + t16;
                        Pl[qq * 64 + (((kk >> 3) ^ (qq & 7)) << 3) + (kk & 7)] =
                            (short)f2bf(s[n2][r_]);
                    }
                }
                #pragma unroll
                for (int ks2 = 0; ks2 < 2; ++ks2) {
                    int kk = ks2 * 32 + g * 8;
                    s16x8 pa = *(const s16x8*)(Pl + t16 * 64 + (((kk >> 3) ^ (t16 & 7)) << 3));
                    int tg = tc * 128 + c4 * 64 + kk;
                    #pragma unroll
                    for (int eo = 0; eo < 4; ++eo) {
                        int e = eo * 16 + t16;
                        int slot = (tg >> 3) ^ (e & 7) ^ ((e >> 3) & 7);
                        s16x8 bv = *(const s16x8*)(Vl + e * 512 + (slot << 3));
                        oacc[eo] = mfma_bf16(pa, bv, oacc[eo]);
                    }
                }
            }
        }
        #pragma unroll
        for (int eo = 0; eo < 4; ++eo)
            #pragma unroll
            for (int r_ = 0; r_ < 4; ++r_) {
                int row = q0 + g * 4 + r_;
                int e = eo * 16 + t16;
                o[((size_t)b * SS + row) * DD + h * HDH + e] =
                    f2bf(oacc[eo][r_] / ls[r_]);
            }
    }
}

extern "C" void kernel_launch(void* const* d_in, const int* in_sizes, int n_in,
                              void* d_out, int out_size, void* d_ws, size_t ws_size,
                              hipStream_t stream)
{
    const int*   tokens = (const int*)d_in[0];
    const int*   mask   = (const int*)d_in[1];
    const float* emb    = (const float*)d_in[2];
    const float* pe     = (const float*)d_in[3];
    const float* Wq     = (const float*)d_in[4];
    const float* Wk     = (const float*)d_in[5];
    const float* Wv     = (const float*)d_in[6];
    const float* Wo     = (const float*)d_in[7];
    const float* l1g    = (const float*)d_in[8];
    const float* l1b    = (const float*)d_in[9];
    const float* W1     = (const float*)d_in[10];
    const float* b1     = (const float*)d_in[11];
    const float* W2     = (const float*)d_in[12];
    const float* b2     = (const float*)d_in[13];
    const float* l2g    = (const float*)d_in[14];
    const float* l2b    = (const float*)d_in[15];

    char* p = (char*)d_ws;
    auto alloc = [&](size_t bytes) { char* r = p; p += (bytes + 255) & ~(size_t)255; return r; };
    unsigned short* wqkv_t = (unsigned short*)alloc((size_t)LL*3*DD*DD*2);
    unsigned short* wo_t   = (unsigned short*)alloc((size_t)LL*DD*DD*2);
    unsigned short* w1_t   = (unsigned short*)alloc((size_t)LL*DD*DFF*2);
    unsigned short* w2_t   = (unsigned short*)alloc((size_t)LL*DD*DFF*2);
    unsigned short* xh     = (unsigned short*)alloc((size_t)MM*DD*2);
    unsigned short* xl     = (unsigned short*)alloc((size_t)MM*DD*2);
    unsigned short* qkvb   = (unsigned short*)alloc((size_t)MM*1536*2);
    unsigned short* obuf   = (unsigned short*)alloc((size_t)MM*DD*2);
    unsigned short* ybufb  = (unsigned short*)alloc((size_t)MM*DD*2);
    unsigned short* hbuf   = qkvb;   // [MM][2048] aliases qkvb+obuf (dead then)

    k_tconv_all<<<4608, 256, 0, stream>>>(Wq, Wk, Wv, Wo, W1, W2,
                                          wqkv_t, wo_t, w1_t, w2_t);
    k_embed<<<8192, 256, 0, stream>>>(tokens, emb, pe, xh, xl);

    hipFuncSetAttribute((const void*)k_attn,
                        hipFuncAttributeMaxDynamicSharedMemorySize, 163840);
    hipFuncSetAttribute((const void*)k_gemm8,
                        hipFuncAttributeMaxDynamicSharedMemorySize, 147456);

    for (int l = 0; l < LL; ++l) {
        const unsigned short* wqkvl = wqkv_t + (size_t)l*3*DD*DD;
        const unsigned short* wol   = wo_t   + (size_t)l*DD*DD;
        const unsigned short* w1l   = w1_t   + (size_t)l*DD*DFF;
        const unsigned short* w2l   = w2_t   + (size_t)l*DD*DFF;

        k_gemm<0><<<1536, 256, 0, stream>>>(xh, wqkvl, qkvb, nullptr, 1536, 512, 12);
        k_attn<<<256, 1024, 163840, stream>>>(qkvb, mask, obuf);
        k_gemm<0><<<512, 256, 0, stream>>>(obuf, wol, ybufb, nullptr, 512, 512, 4);
        k_ln<<<16384, 128, 0, stream>>>(xh, xl, ybufb, l1g + l*DD, l1b + l*DD, nullptr);
        k_gemm<2><<<2048, 256, 0, stream>>>(xh, w1l, hbuf, b1 + (size_t)l*DFF, 2048, 512, 16);
        k_gemm8<<<256, 512, 147456, stream>>>(hbuf, w2l, ybufb, b2 + (size_t)l*DD, 512, 2048, 4);
        float* xout = (l == LL - 1) ? (float*)d_out : nullptr;
        k_ln<<<16384, 128, 0, stream>>>(xh, xl, ybufb, l2g + l*DD, l2b + l*DD, xout);
    }
}